// Round 5
// baseline (3689.250 us; speedup 1.0000x reference)
//
#include <hip/hip_runtime.h>
#include <hip/hip_bf16.h>

// LinearformerBlock on MI355X (gfx950). I/O is FP32 (per reference dtypes);
// internals bf16 MFMA with fp32 accumulation. B=4,N=4096,D=1024,H=4,DH=256,FF=4096.
//
// r1-r4 post-mortem: inputs/outputs are fp32, not bf16 — reading fp32 as bf16
// makes odd elements random-bit bf16s (~1/256 NaN/inf) => the persistent NaN.
// ws = 29.6 MB. d_out (64MB fp32) doubles as scratch: first half = xb (bf16
// cast of x), second half = x2 (bf16). Final dense writes fp32 rows forward-
// order; clobber analysis: chunk R>=8 kills x2 rows <= 2048R-14337, always
// below the next chunk's first needed row 1024(R+1). xb dead after attention.

typedef __hip_bfloat16 bf16;
typedef __attribute__((ext_vector_type(8))) short short8;
typedef __attribute__((ext_vector_type(4))) float floatx4;

__device__ __forceinline__ float b2f(bf16 x) { return __bfloat162float(x); }
__device__ __forceinline__ bf16 f2b(float x) { return __float2bfloat16(x); }
__device__ __forceinline__ float s2f(short s) {
  unsigned int u = ((unsigned int)(unsigned short)s) << 16;
  return __uint_as_float(u);
}
__device__ __forceinline__ short f2s(float f) {
  bf16 h = __float2bfloat16(f);
  return *reinterpret_cast<short*>(&h);
}
__device__ __forceinline__ float gelu_f(float x) {
  float u = 0.7978845608028654f * (x + 0.044715f * x * x * x);
  return 0.5f * x * (1.0f + tanhf(u));
}

// ---------------------------------------------------------------------------
// GEMM: C[m][n] = sum_k A'[m][k] * BT[n][k]   (A' = LN(A) if stats!=null)
// 128x128 tile, BK=32, 4 waves x (4x4) 16x16x32 bf16 MFMA.
// AFP32: A operand is fp32 (LN applied in fp32, packed to bf16 for LDS).
// CFP32: store C as fp32. TRANSC: write C transposed (bf16 only).
// BT operand is always bf16. bias/gamma/beta are fp32. res is bf16, may
// alias C (same-thread read-before-write).
// ---------------------------------------------------------------------------
template <int TRANSC, int AFP32, int CFP32>
__global__ __launch_bounds__(256) void gemm_bt(
    const void* __restrict__ Aop, const bf16* __restrict__ BT, void* Cv,
    int K, int lda, int ldb, int ldc, int zshift,
    long saA, long shA, long saB, long shB, long saC, long shC,
    const float* __restrict__ bias, const bf16* res, int act,
    const float2* stats, const float* __restrict__ gamma,
    const float* __restrict__ beta)
{
  int z = blockIdx.z;
  int zb = z >> zshift, zh = z & ((1 << zshift) - 1);
  long offA = (long)zb * saA + (long)zh * shA;
  long offC = (long)zb * saC + (long)zh * shC;
  const float* Af = (const float*)Aop + offA;
  const bf16*  Ab = (const bf16*)Aop + offA;
  BT += (long)zb * saB + (long)zh * shB;
  bf16*  C  = (bf16*)Cv + offC;
  float* Cf = (float*)Cv + offC;
  if (res) res += offC;
  if (stats) stats += offA / lda;

  __shared__ bf16 As[128 * 32];
  __shared__ bf16 Bs[128 * 32];
  __shared__ bf16 TC[TRANSC ? 128 * 136 : 2];

  const int t = threadIdx.x;
  const int w = t >> 6, l = t & 63;
  const int m0 = blockIdx.y * 128, n0 = blockIdx.x * 128;
  const int wm = (w >> 1) * 64, wn = (w & 1) * 64;
  const int lr = l & 15, lq = l >> 4;

  floatx4 acc[4][4] = {};

  const int sr = t >> 2;        // staging row within half-tile (0..63)
  const int sc = (t & 3) * 8;   // staging col (0,8,16,24)
  const int rowA0 = m0 + sr, rowA1 = m0 + 64 + sr;
  const long o0 = (long)rowA0 * lda + sc;
  const long o1 = (long)rowA1 * lda + sc;

  const bf16* Bp0 = BT + (long)(n0 + sr) * ldb + sc;
  const bf16* Bp1 = BT + (long)(n0 + 64 + sr) * ldb + sc;

  float2 st0, st1;
  if (stats) { st0 = stats[rowA0]; st1 = stats[rowA1]; }

  for (int k0 = 0; k0 < K; k0 += 32) {
    short8 ra0, ra1;
    if constexpr (AFP32) {
      float4 a00 = *(const float4*)(Af + o0 + k0);
      float4 a01 = *(const float4*)(Af + o0 + k0 + 4);
      float4 a10 = *(const float4*)(Af + o1 + k0);
      float4 a11 = *(const float4*)(Af + o1 + k0 + 4);
      float v0[8] = {a00.x, a00.y, a00.z, a00.w, a01.x, a01.y, a01.z, a01.w};
      float v1[8] = {a10.x, a10.y, a10.z, a10.w, a11.x, a11.y, a11.z, a11.w};
      if (stats) {
        float4 g0 = *(const float4*)(gamma + k0 + sc);
        float4 g1 = *(const float4*)(gamma + k0 + sc + 4);
        float4 e0 = *(const float4*)(beta + k0 + sc);
        float4 e1 = *(const float4*)(beta + k0 + sc + 4);
        float gv[8] = {g0.x, g0.y, g0.z, g0.w, g1.x, g1.y, g1.z, g1.w};
        float ev[8] = {e0.x, e0.y, e0.z, e0.w, e1.x, e1.y, e1.z, e1.w};
#pragma unroll
        for (int i = 0; i < 8; i++) {
          v0[i] = (v0[i] - st0.x) * st0.y * gv[i] + ev[i];
          v1[i] = (v1[i] - st1.x) * st1.y * gv[i] + ev[i];
        }
      }
#pragma unroll
      for (int i = 0; i < 8; i++) { ra0[i] = f2s(v0[i]); ra1[i] = f2s(v1[i]); }
    } else {
      ra0 = *(const short8*)(Ab + o0 + k0);
      ra1 = *(const short8*)(Ab + o1 + k0);
      if (stats) {
        float4 g0 = *(const float4*)(gamma + k0 + sc);
        float4 g1 = *(const float4*)(gamma + k0 + sc + 4);
        float4 e0 = *(const float4*)(beta + k0 + sc);
        float4 e1 = *(const float4*)(beta + k0 + sc + 4);
        float gv[8] = {g0.x, g0.y, g0.z, g0.w, g1.x, g1.y, g1.z, g1.w};
        float ev[8] = {e0.x, e0.y, e0.z, e0.w, e1.x, e1.y, e1.z, e1.w};
#pragma unroll
        for (int i = 0; i < 8; i++) {
          ra0[i] = f2s((s2f(ra0[i]) - st0.x) * st0.y * gv[i] + ev[i]);
          ra1[i] = f2s((s2f(ra1[i]) - st1.x) * st1.y * gv[i] + ev[i]);
        }
      }
    }
    short8 rb0 = *(const short8*)(Bp0 + k0);
    short8 rb1 = *(const short8*)(Bp1 + k0);
    __syncthreads();  // prev iter's LDS reads done
    *(short8*)&As[t * 8]        = ra0;
    *(short8*)&As[2048 + t * 8] = ra1;
    *(short8*)&Bs[t * 8]        = rb0;
    *(short8*)&Bs[2048 + t * 8] = rb1;
    __syncthreads();
    short8 af[4], bfr[4];
#pragma unroll
    for (int i = 0; i < 4; i++) {
      af[i]  = *(const short8*)&As[(wm + i * 16 + lr) * 32 + lq * 8];
      bfr[i] = *(const short8*)&Bs[(wn + i * 16 + lr) * 32 + lq * 8];
    }
#pragma unroll
    for (int i = 0; i < 4; i++)
#pragma unroll
      for (int j = 0; j < 4; j++)
        acc[i][j] = __builtin_amdgcn_mfma_f32_16x16x32_bf16(af[i], bfr[j], acc[i][j], 0, 0, 0);
  }

  if constexpr (TRANSC) {
    // C/D layout: col(n) = lane&15, row(m) = (lane>>4)*4 + reg.
#pragma unroll
    for (int i = 0; i < 4; i++) {
      int rloc = wm + i * 16 + lq * 4;
#pragma unroll
      for (int j = 0; j < 4; j++) {
        int cloc = wn + j * 16 + lr;
#pragma unroll
        for (int r = 0; r < 4; r++)
          TC[cloc * 136 + rloc + r] = f2b(acc[i][j][r]);
      }
    }
    __syncthreads();
    long base = (long)n0 * ldc + m0;
#pragma unroll
    for (int p = 0; p < 8; p++) {
      int er = (t >> 4) + p * 16;   // local e row (0..127)
      int mc = (t & 15) * 8;        // local m col
      *(short8*)(C + base + (long)er * ldc + mc) = *(const short8*)&TC[er * 136 + mc];
    }
    return;
  }

#pragma unroll
  for (int i = 0; i < 4; i++) {
    int row0 = m0 + wm + i * 16 + lq * 4;
#pragma unroll
    for (int j = 0; j < 4; j++) {
      int col = n0 + wn + j * 16 + lr;
      float bv = bias ? bias[col] : 0.0f;
#pragma unroll
      for (int r = 0; r < 4; r++) {
        float v = acc[i][j][r] + bv;
        long idx = (long)(row0 + r) * ldc + col;
        if (res) v += b2f(res[idx]);
        if (act) v = gelu_f(v);
        if constexpr (CFP32) Cf[idx] = v; else C[idx] = f2b(v);
      }
    }
  }
}

// ---------------------------------------------------------------------------
// Tiled transpose fp32 -> bf16: dst[c][r] = (bf16)src[r][c].
// Grid: (Csrc/32, Rsrc/32). Block (32,8).
// ---------------------------------------------------------------------------
__global__ void transpose_f2b(const float* __restrict__ src, bf16* __restrict__ dst,
                              int lsrc, int ldst)
{
  __shared__ bf16 tile[32][33];
  int tx = threadIdx.x, ty = threadIdx.y;
  int c0 = blockIdx.x * 32, r0 = blockIdx.y * 32;
#pragma unroll
  for (int j = 0; j < 4; j++)
    tile[ty + j * 8][tx] = f2b(src[(long)(r0 + ty + j * 8) * lsrc + c0 + tx]);
  __syncthreads();
#pragma unroll
  for (int j = 0; j < 4; j++)
    dst[(long)(c0 + ty + j * 8) * ldst + r0 + tx] = tile[tx][ty + j * 8];
}

// convert fp32 -> bf16, 8 elems/thread.
__global__ __launch_bounds__(256) void cvt_f2b(const float* __restrict__ s,
                                               bf16* __restrict__ d)
{
  long i = ((long)blockIdx.x * 256 + threadIdx.x) * 8;
  float4 a = *(const float4*)(s + i);
  float4 b = *(const float4*)(s + i + 4);
  short8 o;
  o[0] = f2s(a.x); o[1] = f2s(a.y); o[2] = f2s(a.z); o[3] = f2s(a.w);
  o[4] = f2s(b.x); o[5] = f2s(b.y); o[6] = f2s(b.z); o[7] = f2s(b.w);
  *(short8*)(d + i) = o;
}

// LN stats over D=1024: stats[row] = {mean, rsqrt(var+eps)}. fp32 input.
__global__ __launch_bounds__(256) void ln_stats_f32(
    const float* __restrict__ x, float2* __restrict__ stats)
{
  int row = blockIdx.x, t = threadIdx.x;
  const float* xr = x + (long)row * 1024;
  float4 a = *(const float4*)(xr + t * 4);
  float s = a.x + a.y + a.z + a.w;
  float q = a.x * a.x + a.y * a.y + a.z * a.z + a.w * a.w;
  for (int o = 32; o > 0; o >>= 1) { s += __shfl_down(s, o); q += __shfl_down(q, o); }
  __shared__ float sm[8];
  if ((t & 63) == 0) { sm[t >> 6] = s; sm[4 + (t >> 6)] = q; }
  __syncthreads();
  if (t == 0) {
    s = sm[0] + sm[1] + sm[2] + sm[3];
    q = sm[4] + sm[5] + sm[6] + sm[7];
    float mean = s * (1.0f / 1024.0f);
    float var  = q * (1.0f / 1024.0f) - mean * mean;
    stats[row] = make_float2(mean, rsqrtf(var + 1e-5f));
  }
}

// LN stats, bf16 input.
__global__ __launch_bounds__(256) void ln_stats_b16(
    const bf16* __restrict__ x, float2* __restrict__ stats)
{
  int row = blockIdx.x, t = threadIdx.x;
  const bf16* xr = x + (long)row * 1024;
  float v[4];
#pragma unroll
  for (int i = 0; i < 4; i++) v[i] = b2f(xr[t * 4 + i]);
  float s = v[0] + v[1] + v[2] + v[3];
  float q = v[0] * v[0] + v[1] * v[1] + v[2] * v[2] + v[3] * v[3];
  for (int o = 32; o > 0; o >>= 1) { s += __shfl_down(s, o); q += __shfl_down(q, o); }
  __shared__ float sm[8];
  if ((t & 63) == 0) { sm[t >> 6] = s; sm[4 + (t >> 6)] = q; }
  __syncthreads();
  if (t == 0) {
    s = sm[0] + sm[1] + sm[2] + sm[3];
    q = sm[4] + sm[5] + sm[6] + sm[7];
    float mean = s * (1.0f / 1024.0f);
    float var  = q * (1.0f / 1024.0f) - mean * mean;
    stats[row] = make_float2(mean, rsqrtf(var + 1e-5f));
  }
}

// softmax over 256 contiguous elems per row (q~, per-head). In place, bf16.
__global__ __launch_bounds__(256) void qsoftmax256(bf16* __restrict__ q)
{
  long idx = (long)blockIdx.x * 256 + threadIdx.x;
  int t = threadIdx.x;
  float v = expf(0.25f * b2f(q[idx]));
  float s = v;
  for (int o = 32; o > 0; o >>= 1) s += __shfl_down(s, o);
  __shared__ float sm[4];
  if ((t & 63) == 0) sm[t >> 6] = s;
  __syncthreads();
  float tot = sm[0] + sm[1] + sm[2] + sm[3];
  q[idx] = f2b(v / tot);
}

// k softmax on kT [rows][4096]: row-softmax exp(0.25x)/rowsum, in place.
__global__ __launch_bounds__(256) void ksoftmaxT(bf16* __restrict__ kT)
{
  long base = (long)blockIdx.x * 4096;
  int t = threadIdx.x;
  float loc[16];
  float s = 0.0f;
#pragma unroll
  for (int i = 0; i < 16; i++) {
    loc[i] = expf(0.25f * b2f(kT[base + t + i * 256]));
    s += loc[i];
  }
  for (int o = 32; o > 0; o >>= 1) s += __shfl_down(s, o);
  __shared__ float sm[4];
  if ((t & 63) == 0) sm[t >> 6] = s;
  __syncthreads();
  float inv = 1.0f / (sm[0] + sm[1] + sm[2] + sm[3]);
#pragma unroll
  for (int i = 0; i < 16; i++)
    kT[base + t + i * 256] = f2b(loc[i] * inv);
}

// ctx reduce: CTX[i] = sum_kc G[kc*262144 + i], i in [0, 262144).
__global__ __launch_bounds__(256) void reduce_ctx(
    const bf16* __restrict__ G, bf16* __restrict__ CTX)
{
  long i = (long)blockIdx.x * 256 + threadIdx.x;
  float s = 0.0f;
#pragma unroll
  for (int kc = 0; kc < 8; kc++) s += b2f(G[kc * 262144 + i]);
  CTX[i] = f2b(s);
}

extern "C" void kernel_launch(void* const* d_in, const int* in_sizes, int n_in,
                              void* d_out, int out_size, void* d_ws, size_t ws_size,
                              hipStream_t stream) {
  const float* x    = (const float*)d_in[0];
  const float* ln1g = (const float*)d_in[1];
  const float* ln1b = (const float*)d_in[2];
  const float* wq   = (const float*)d_in[3];
  const float* wk   = (const float*)d_in[4];
  const float* wv   = (const float*)d_in[5];
  const float* wo   = (const float*)d_in[6];
  const float* bo   = (const float*)d_in[7];
  const float* ln2g = (const float*)d_in[8];
  const float* ln2b = (const float*)d_in[9];
  const float* wff1 = (const float*)d_in[10];
  const float* bff1 = (const float*)d_in[11];
  const float* wff2 = (const float*)d_in[12];
  const float* bff2 = (const float*)d_in[13];
  const float* wd   = (const float*)d_in[14];
  const float* bd   = (const float*)d_in[15];

  // d_out (64MB fp32) as scratch: first half xb (bf16 x), second half x2 (bf16).
  bf16* xb = (bf16*)d_out;                            // 16384x1024 bf16
  bf16* x2 = (bf16*)d_out + (size_t)16384 * 1024;     // 16384x1024 bf16
  float* outf = (float*)d_out;

  char* wsp = (char*)d_ws;
  size_t off = 0;
  auto alloc = [&](size_t bytes) -> void* {
    void* p = wsp + off; off += (bytes + 255) & ~(size_t)255; return p;
  };
  bf16*   S1  = (bf16*)alloc((size_t)8 * 1024 * 1024);   // kT_h -> q_h | wff1T
  bf16*   S2  = (bf16*)alloc((size_t)8 * 1024 * 1024);   // vT_h -> attn_h | wff2T
  bf16*   G   = (bf16*)alloc((size_t)8 * 1024 * 1024);   // ctx partials | g chunk
  bf16*   CTX = (bf16*)alloc((size_t)4 * 256 * 256 * 2); // ctx_h [4b][256e][256d]
  bf16*   W1  = (bf16*)alloc((size_t)1024 * 256 * 2);    // weight slice (BT form)
  bf16*   WDT = (bf16*)alloc((size_t)1024 * 1024 * 2);   // wd^T
  bf16*   X3  = (bf16*)alloc((size_t)1024 * 1024 * 2);   // x3 row-chunk
  float2* st1 = (float2*)alloc((size_t)16384 * 8);
  float2* st2 = (float2*)alloc((size_t)16384 * 8);
  // total ws ~29.6 MB

  const long SA = (long)4096 * 1024;  // x batch stride (elements)
  const long PH = (long)256 * 4096;   // per-batch [e][n] stride
  dim3 tb(32, 8);
  const bf16* nb = nullptr;

  // ---- xb = bf16(x); LN1 stats (fp32 x) ----
  cvt_f2b<<<8192, 256, 0, stream>>>(x, xb);
  ln_stats_f32<<<16384, 256, 0, stream>>>(x, st1);

  // ---- attention, per head; x2 accumulates into second half of d_out ----
  for (int h = 0; h < 4; h++) {
    // kT_h = (LN1(x) @ wk[:,h])^T -> S1 [4b][256e][4096n]; row softmax
    transpose_f2b<<<dim3(8, 32), tb, 0, stream>>>(wk + h * 256, W1, 1024, 1024);
    gemm_bt<1, 1, 0><<<dim3(2, 32, 4), 256, 0, stream>>>(x, W1, S1,
        1024, 1024, 1024, 4096, 2, 0, SA, 0, 0, 0, PH,
        nullptr, nb, 0, st1, ln1g, ln1b);
    ksoftmaxT<<<1024, 256, 0, stream>>>(S1);

    // vT_h -> S2
    transpose_f2b<<<dim3(8, 32), tb, 0, stream>>>(wv + h * 256, W1, 1024, 1024);
    gemm_bt<1, 1, 0><<<dim3(2, 32, 4), 256, 0, stream>>>(x, W1, S2,
        1024, 1024, 1024, 4096, 2, 0, SA, 0, 0, 0, PH,
        nullptr, nb, 0, st1, ln1g, ln1b);

    // ctx partials: G[kc][b][e][d] = sum_{n in kc} vT[e][n] * k~T[d][n]
    gemm_bt<0, 0, 0><<<dim3(2, 2, 32), 256, 0, stream>>>(S2, S1, G,
        512, 4096, 4096, 256, 3, PH, 512, PH, 512, 65536, 262144,
        nullptr, nb, 0, nullptr, nullptr, nullptr);
    reduce_ctx<<<1024, 256, 0, stream>>>(G, CTX);

    // q_h = LN1(x)@wq[:,h] -> S1 [4b][4096][256]; softmax over dh
    transpose_f2b<<<dim3(8, 32), tb, 0, stream>>>(wq + h * 256, W1, 1024, 1024);
    gemm_bt<0, 1, 0><<<dim3(2, 32, 4), 256, 0, stream>>>(x, W1, S1,
        1024, 1024, 1024, 256, 2, 0, SA, 0, 0, 0, (long)4096 * 256,
        nullptr, nb, 0, st1, ln1g, ln1b);
    qsoftmax256<<<16384, 256, 0, stream>>>(S1);

    // attn_h[n][e] = sum_d q~[n][d] * ctx[e][d] -> S2 [4b][4096][256]
    gemm_bt<0, 0, 0><<<dim3(2, 32, 4), 256, 0, stream>>>(S1, CTX, S2,
        256, 256, 256, 256, 2, 0, (long)4096 * 256, 0, 65536, 0, (long)4096 * 256,
        nullptr, nb, 0, nullptr, nullptr, nullptr);

    // x2 += attn_h @ wo[h rows]  (h==0 seeds xb + bo)
    transpose_f2b<<<dim3(32, 8), tb, 0, stream>>>(wo + (size_t)h * 256 * 1024, W1, 1024, 256);
    gemm_bt<0, 0, 0><<<dim3(8, 128, 1), 256, 0, stream>>>(S2, W1, x2,
        256, 256, 256, 1024, 2, 0, 0, 0, 0, 0, 0,
        (h == 0) ? bo : nullptr, (h == 0) ? xb : x2, 0, nullptr, nullptr, nullptr);
  }

  // ---- FFN + trailing dense, row-chunked (1024 rows x 16) ----
  ln_stats_b16<<<16384, 256, 0, stream>>>(x2, st2);
  transpose_f2b<<<dim3(128, 32), tb, 0, stream>>>(wff1, S1, 4096, 1024);  // S1 = wff1T
  transpose_f2b<<<dim3(32, 128), tb, 0, stream>>>(wff2, S2, 1024, 4096);  // S2 = wff2T
  transpose_f2b<<<dim3(32, 32), tb, 0, stream>>>(wd, WDT, 1024, 1024);

  for (int R = 0; R < 16; R++) {
    const bf16* xr = x2 + (size_t)R * 1024 * 1024;  // x2 rows (bf16)
    // g = gelu(LN2(x2_R) @ wff1T + b1) -> G [1024][4096]
    gemm_bt<0, 0, 0><<<dim3(32, 8, 1), 256, 0, stream>>>(xr, S1, G,
        1024, 1024, 1024, 4096, 2, 0, 0, 0, 0, 0, 0,
        bff1, nb, 1, st2 + R * 1024, ln2g, ln2b);
    // x3_R = x2_R + g @ wff2T + b2 -> X3 (bf16)
    gemm_bt<0, 0, 0><<<dim3(8, 8, 1), 256, 0, stream>>>(G, S2, X3,
        4096, 4096, 4096, 1024, 2, 0, 0, 0, 0, 0, 0,
        bff2, xr, 0, nullptr, nullptr, nullptr);
    // out_R = x3_R @ wd + bd -> d_out rows R (fp32). Forward order: clobbers
    // only xb (dead) and already-consumed x2 rows (see header analysis).
    gemm_bt<0, 0, 1><<<dim3(8, 8, 1), 256, 0, stream>>>(X3, WDT,
        outf + (size_t)R * 1024 * 1024,
        1024, 1024, 1024, 1024, 2, 0, 0, 0, 0, 0, 0,
        bd, nb, 0, nullptr, nullptr, nullptr);
  }
}